// Round 14
// baseline (1888.720 us; speedup 1.0000x reference)
//
#include <hip/hip_runtime.h>

// Problem constants
#define HW    128
#define NCELL 16
#define ABUF_PER_CELL 23040   // 3 slots * 5 chunks * 4 quads * 48 co * 8

typedef _Float16 half8 __attribute__((ext_vector_type(8)));
typedef _Float16 half4 __attribute__((ext_vector_type(4)));
typedef float    f32x4 __attribute__((ext_vector_type(4)));

// 16B-granular XOR swizzle (bijective within 64-unit groups)
__device__ __forceinline__ int swz(int u) { return u ^ ((u >> 3) & 7); }

// ---------------------------------------------------------------------------
// Weight prep: W[cell][co][ci][kh][kw] fp32 -> slot-major A-fragment fp16
// (RTN). Abuf: [cell][slot3][chunk5][quad4][co48][j8]; k-group g = chunk*4 +
// quad -> (kh=g/6, kw=(g%6)/2, cg=g&1), ci = slot*16 + cg*8 + j; g>=18 -> 0.
// (Validated rounds 11-13: absmax 4.88e-4.)
// ---------------------------------------------------------------------------
__global__ void prep_w_k(const float* __restrict__ W, _Float16* __restrict__ Abuf) {
    int idx = blockIdx.x * 256 + threadIdx.x;
    if (idx >= NCELL * ABUF_PER_CELL) return;
    int j = idx & 7;
    int t = idx >> 3;
    int co = t % 48;   t /= 48;
    int quad = t & 3;  t >>= 2;
    int chunk = t % 5; t /= 5;
    int slot = t % 3;  t /= 3;
    int cell = t;
    int g = chunk * 4 + quad;
    float v = 0.f;
    if (g < 18) {
        int kh = g / 6, r6 = g % 6;
        int kw = r6 >> 1, cg = r6 & 1;
        int ci = slot * 16 + cg * 8 + j;
        v = W[((size_t)(cell * 48 + co) * 48 + ci) * 9 + kh * 3 + kw];
    }
    Abuf[idx] = (_Float16)v;
}

// ---------------------------------------------------------------------------
// Input conversion: x fp32 NCHW -> fp16 NHWC [8][128][128][16] into X.
// ---------------------------------------------------------------------------
__global__ void x_prep_k(const float* __restrict__ x, _Float16* __restrict__ X) {
    int tid = threadIdx.x;
    int x0 = blockIdx.x * 16, y0 = blockIdx.y * 16, b = blockIdx.z;
    int py = tid >> 4, px = tid & 15;
    int y = y0 + py, xg = x0 + px;
    half8 v0, v1;
#pragma unroll
    for (int c = 0; c < 16; ++c) {
        float v = x[(((size_t)b * 16 + c) * HW + y) * HW + xg];
        if (c < 8) v0[c] = (_Float16)v; else v1[c - 8] = (_Float16)v;
    }
    _Float16* dst = X + (((size_t)b * HW + y) * HW + xg) * 16;
    *(half8*)dst = v0; *(half8*)(dst + 8) = v1;
}

// Per-cell I/O descriptor. Streams: fp16 NHWC. fout: final fp32 NCHW output.
struct CellIO {
    const _Float16* in0; const _Float16* in1; const _Float16* in2;
    const _Float16* Ac; const float* bc;
    _Float16* o0; _Float16* o1; _Float16* o2;
    float* fout;
};

struct SweepParams { CellIO io[NCELL]; int* flags; };

// ---------------------------------------------------------------------------
// One grid-cell conv body (r13 RPW4 code, validated): slot-major implicit
// GEMM, fp16 A x fp16 B, fp32 accumulate. One staging phase, one barrier.
// Block: 256 thr = 4 waves; wave w: rows 4w..4w+3 of a 16x16 px tile.
// ---------------------------------------------------------------------------
template<int LIVE, int NIN, bool FIN>
__device__ __forceinline__ void cell_body(const CellIO& P, int b, _Float16* xh)
{
    const int tid = threadIdx.x;
    const int x0 = blockIdx.x * 16, y0 = blockIdx.y * 16;
    const int lane = tid & 63, wv = tid >> 6;
    const int n = lane & 15, quad = lane >> 4;
    const int py0 = wv * 4;

    // ---- stage NIN slots: 324 px-tasks; NHWC fp16 -> pure wide copies ----
    const _Float16* const ins[3] = {P.in0, P.in1, P.in2};
    for (int task = tid; task < 324; task += 256) {
        int iy = task / 18, ix = task - (task / 18) * 18;
        int gy = y0 + iy - 1, gx = x0 + ix - 1;
        bool inb = (unsigned)gy < (unsigned)HW && (unsigned)gx < (unsigned)HW;
#pragma unroll
        for (int s = 0; s < NIN; ++s) {
            half8 v0 = {0, 0, 0, 0, 0, 0, 0, 0};
            half8 v1 = {0, 0, 0, 0, 0, 0, 0, 0};
            if (inb) {
                const _Float16* sp = ins[s] + (((size_t)b * HW + gy) * HW + gx) * 16;
                v0 = *(const half8*)sp;
                v1 = *(const half8*)(sp + 8);
            }
            _Float16* dst = xh + s * 5184;
            *(half8*)(dst + swz(task * 2) * 8)     = v0;
            *(half8*)(dst + swz(task * 2 + 1) * 8) = v1;
        }
    }
    __syncthreads();

    // Per-chunk B-read base (validated). Dead groups (g>=18) -> g=0 (A zero).
    int base_c[5];
#pragma unroll
    for (int c = 0; c < 5; ++c) {
        int g = c * 4 + quad;
        if (g >= 18) g = 0;
        int kh = g / 6, r6 = g % 6;
        int kw = r6 >> 1, cg = r6 & 1;
        base_c[c] = ((py0 + kh) * 18 + n + kw) * 2 + cg;
    }

    f32x4 acc[3][4];
#pragma unroll
    for (int cot = 0; cot < 3; ++cot) {
        if (!(LIVE & (1 << cot))) continue;
#pragma unroll
        for (int r = 0; r < 4; ++r) {
            float bv = P.bc[cot * 16 + quad * 4 + r];
#pragma unroll
            for (int nt = 0; nt < 4; ++nt) acc[cot][nt][r] = bv;
        }
    }

    // ---- K loop: NIN slots x 5 chunks, fully unrolled, no barriers ----
#pragma unroll
    for (int s = 0; s < NIN; ++s) {
        const _Float16* sxh = xh + s * 5184;
        const _Float16* As = P.Ac + (size_t)(s * 5) * 1536 + quad * 384 + n * 8;
#pragma unroll
        for (int c = 0; c < 5; ++c) {
            half8 Bh[4];
#pragma unroll
            for (int nt = 0; nt < 4; ++nt)
                Bh[nt] = *(const half8*)(sxh + swz(base_c[c] + nt * 36) * 8);
            const _Float16* Ab = As + (size_t)c * 1536;
#pragma unroll
            for (int cot = 0; cot < 3; ++cot) {
                if (!(LIVE & (1 << cot))) continue;
                half8 ah = *(const half8*)(Ab + cot * 128);
#pragma unroll
                for (int nt = 0; nt < 4; ++nt)
                    acc[cot][nt] = __builtin_amdgcn_mfma_f32_16x16x32_f16(ah, Bh[nt], acc[cot][nt], 0, 0, 0);
            }
        }
    }

    // ---- epilogue ----
    if constexpr (FIN) {
#pragma unroll
        for (int nt = 0; nt < 4; ++nt) {
            int y = y0 + py0 + nt, xg = x0 + n;
#pragma unroll
            for (int r = 0; r < 4; ++r) {
                float vv = acc[0][nt][r];
                P.fout[(((size_t)b * 16 + quad * 4 + r) * HW + y) * HW + xg] = vv > 0.f ? vv : 0.f;
            }
        }
    } else {
        _Float16* const outs[3] = {P.o0, P.o1, P.o2};
#pragma unroll
        for (int cot = 0; cot < 3; ++cot) {
            if (!(LIVE & (1 << cot))) continue;
            _Float16* op = outs[cot];
#pragma unroll
            for (int nt = 0; nt < 4; ++nt) {
                int y = y0 + py0 + nt;
                half4 hv;
#pragma unroll
                for (int r = 0; r < 4; ++r) {
                    float vv = acc[cot][nt][r];
                    hv[r] = (_Float16)(vv > 0.f ? vv : 0.f);
                }
                *(half4*)(op + (((size_t)b * HW + y) * HW + x0 + n) * 16 + quad * 4) = hv;
            }
        }
    }
}

// ---------------------------------------------------------------------------
// Persistent tile-dataflow sweep: 512 blocks (one per 16x16 tile x batch),
// each runs all 16 cells in column-major (topological) order. Producer->
// consumer ordering via per-(cell,tile) flags: consumer waits on each
// producer's 3x3 neighbor tiles (halo = 1 px). Co-residency: 512 blocks at
// >=2 blocks/CU (LDS 31.1 KB, launch_bounds(256,2)) -> all resident, no
// deadlock. Release: fence + barrier + agent release-store; acquire spin +
// barrier (sanctioned device-scope pattern for non-coherent XCD L2s).
// ---------------------------------------------------------------------------
__global__ __launch_bounds__(256, 2) void sweep_k(SweepParams SP) {
    __shared__ __align__(16) _Float16 xh[3 * 5184];
    const int bx = blockIdx.x, by = blockIdx.y, b = blockIdx.z;
    const int tile = bx + 8 * (by + 8 * b);
    int* flags = SP.flags;
    const int tid = threadIdx.x;

    auto wait3 = [&](int d0, int d1, int d2, int nd) {
        if (tid < nd * 9) {
            int p = tid / 9, k = tid - p * 9;
            int dep = (p == 0) ? d0 : (p == 1) ? d1 : d2;
            int nbx = bx + (k % 3) - 1, nby = by + (k / 3) - 1;
            if ((unsigned)nbx < 8u && (unsigned)nby < 8u) {
                int idx = dep * 512 + nbx + 8 * (nby + 8 * b);
                while (__hip_atomic_load(&flags[idx], __ATOMIC_ACQUIRE,
                                         __HIP_MEMORY_SCOPE_AGENT) == 0)
                    __builtin_amdgcn_s_sleep(8);
            }
        }
        __syncthreads();
        __threadfence();
    };
    auto done = [&](int cell) {
        __threadfence();
        __syncthreads();
        if (tid == 0)
            __hip_atomic_store(&flags[cell * 512 + tile], 1, __ATOMIC_RELEASE,
                               __HIP_MEMORY_SCOPE_AGENT);
    };

    // Column-major cell order; dep ids all < cell id (topological, verified).
    /* id0  (0,0) */                       cell_body<5,1,false>(SP.io[0],  b, xh); done(0);
    /* id1  (0,1) */ wait3(0,0,0,1);       cell_body<7,1,false>(SP.io[1],  b, xh); done(1);
    /* id2  (0,2) */ wait3(1,0,0,1);       cell_body<7,1,false>(SP.io[2],  b, xh); done(2);
    /* id3  (0,3) */ wait3(2,0,0,1);       cell_body<3,1,false>(SP.io[3],  b, xh); done(3);
    /* id4  (1,0) */ wait3(0,1,0,2);       cell_body<5,2,false>(SP.io[4],  b, xh); done(4);
    /* id5  (1,1) */ wait3(1,2,4,3);       cell_body<7,3,false>(SP.io[5],  b, xh); done(5);
    /* id6  (1,2) */ wait3(2,3,5,3);       cell_body<7,3,false>(SP.io[6],  b, xh); done(6);
    /* id7  (1,3) */ wait3(3,6,0,2);       cell_body<3,2,false>(SP.io[7],  b, xh); done(7);
    /* id8  (2,0) */ wait3(4,5,0,2);       cell_body<5,2,false>(SP.io[8],  b, xh); done(8);
    /* id9  (2,1) */ wait3(5,6,8,3);       cell_body<7,3,false>(SP.io[9],  b, xh); done(9);
    /* id10 (2,2) */ wait3(6,7,9,3);       cell_body<7,3,false>(SP.io[10], b, xh); done(10);
    /* id11 (2,3) */ wait3(7,10,0,2);      cell_body<3,2,false>(SP.io[11], b, xh); done(11);
    /* id12 (3,0) */ wait3(8,9,0,2);       cell_body<4,2,false>(SP.io[12], b, xh); done(12);
    /* id13 (3,1) */ wait3(9,10,12,3);     cell_body<4,3,false>(SP.io[13], b, xh); done(13);
    /* id14 (3,2) */ wait3(10,11,13,3);    cell_body<4,3,false>(SP.io[14], b, xh); done(14);
    /* id15 (3,3) */ wait3(11,14,0,2);     cell_body<1,2,true >(SP.io[15], b, xh);
}

// ---------------------------------------------------------------------------
// Orchestration: 4 dispatches total: flag-zero memset -> prep_w -> x_prep ->
// persistent sweep. Buffers (fp16 NHWC, 4.2 MB each): X, R[colpar][row] x8,
// U[1..3] x3, D[col][rowpar] x8 (PER-COLUMN down pairs — required for WAR
// safety under dataflow: shared-D ping-pong races when tiles pipeline).
// WAR audit: every buffer's next writer directly depends on its unique
// reader at +-1 tile (R: (c+2,r)<-(c+1,r); U[r]: (c+1,r)<-(c+1,r-1) via down;
// D[c]: (c,r+2)<-(c,r+1); X: (1,0)<-(0,0)). ws ~85 MB (<127 MB known avail).
// ---------------------------------------------------------------------------
extern "C" void kernel_launch(void* const* d_in, const int* in_sizes, int n_in,
                              void* d_out, int out_size, void* d_ws, size_t ws_size,
                              hipStream_t stream) {
    const float* x  = (const float*)d_in[0];   // [8,16,128,128]
    const float* W  = (const float*)d_in[1];   // [4,4,48,48,3,3]
    const float* bi = (const float*)d_in[2];   // [4,4,48]
    float* out = (float*)d_out;                // [8,16,128,128]

    _Float16* Abuf = (_Float16*)d_ws;
    const size_t abytes = (size_t)NCELL * ABUF_PER_CELL * 2;   // 0.74 MB
    int* flags = (int*)((char*)d_ws + abytes);                 // 16*512 ints
    const size_t fbytes = (size_t)NCELL * 512 * sizeof(int);   // 32 KB
    _Float16* q = (_Float16*)((char*)flags + fbytes);
    const size_t S = (size_t)8 * HW * HW * 16;                 // halfs/buffer

    _Float16 *X, *R[2][4], *U[4], *D[4][2];
    X = q; q += S;
    for (int pa = 0; pa < 2; ++pa)
        for (int r = 0; r < 4; ++r) { R[pa][r] = q; q += S; }
    U[0] = nullptr;
    for (int r = 1; r < 4; ++r) { U[r] = q; q += S; }
    for (int c = 0; c < 4; ++c)
        for (int d2 = 0; d2 < 2; ++d2) { D[c][d2] = q; q += S; }

    // Zero the dependency flags every call (mandatory; graph-capturable).
    hipMemsetAsync((void*)flags, 0, fbytes, stream);

    hipLaunchKernelGGL(prep_w_k, dim3((NCELL * ABUF_PER_CELL + 255) / 256),
                       dim3(256), 0, stream, W, Abuf);
    hipLaunchKernelGGL(x_prep_k, dim3(8, 8, 8), dim3(256), 0, stream, x, X);

    SweepParams SP{};
    SP.flags = flags;
    for (int c = 0; c < 4; ++c) {
        for (int r = 0; r < 4; ++r) {
            CellIO io{};
            if (c == 0) {
                io.in0 = (r == 0) ? X : D[0][(r - 1) & 1];
            } else {
                io.in0 = R[(c - 1) & 1][r];
                if (r == 0)      io.in1 = U[1];
                else if (r == 3) io.in1 = D[c][0];
                else { io.in1 = U[r + 1]; io.in2 = D[c][(r - 1) & 1]; }
            }
            if (c < 3) {
                io.o0 = R[c & 1][r];
                if (r > 0) io.o1 = U[r];
                if (r < 3) io.o2 = D[c][r & 1];
            } else {
                if (r < 3) io.o2 = D[3][r & 1];
                else       io.fout = out;
            }
            io.Ac = Abuf + (size_t)(c * 4 + r) * ABUF_PER_CELL;
            io.bc = bi + (size_t)(c * 4 + r) * 48;
            SP.io[c * 4 + r] = io;
        }
    }

    hipLaunchKernelGGL(sweep_k, dim3(8, 8, 8), dim3(256), 0, stream, SP);
}

// Round 15
// 207.809 us; speedup vs baseline: 9.0887x; 9.0887x over previous
//
#include <hip/hip_runtime.h>

// Problem constants
#define HW    128
#define PW    130          // padded stream pitch (1-px zero border)
#define NCELL 16
#define ABUF_PER_CELL 23040   // 3 slots * 5 chunks * 4 quads * 48 co * 8

typedef _Float16 half8 __attribute__((ext_vector_type(8)));
typedef _Float16 half4 __attribute__((ext_vector_type(4)));
typedef float    f32x4 __attribute__((ext_vector_type(4)));

// 16B-granular XOR swizzle (involution: bits0-2 ^= bits3-5)
__device__ __forceinline__ int swz(int u) { return u ^ ((u >> 3) & 7); }

// async global->LDS, 16 B per lane; LDS dest = wave-uniform base + lane*16
#define GLD_LDS(gp, lp) __builtin_amdgcn_global_load_lds( \
    (const __attribute__((address_space(1))) void*)(gp),  \
    (__attribute__((address_space(3))) void*)(lp), 16, 0, 0)

// ---------------------------------------------------------------------------
// Weight prep: W[cell][co][ci][kh][kw] fp32 -> slot-major A-fragment fp16
// (RTN). Abuf: [cell][slot3][chunk5][quad4][co48][j8]; k-group g = chunk*4 +
// quad -> (kh=g/6, kw=(g%6)/2, cg=g&1), ci = slot*16 + cg*8 + j; g>=18 -> 0.
// (Validated rounds 11-13: absmax 4.88e-4.)
// ---------------------------------------------------------------------------
__global__ void prep_w_k(const float* __restrict__ W, _Float16* __restrict__ Abuf) {
    int idx = blockIdx.x * 256 + threadIdx.x;
    if (idx >= NCELL * ABUF_PER_CELL) return;
    int j = idx & 7;
    int t = idx >> 3;
    int co = t % 48;   t /= 48;
    int quad = t & 3;  t >>= 2;
    int chunk = t % 5; t /= 5;
    int slot = t % 3;  t /= 3;
    int cell = t;
    int g = chunk * 4 + quad;
    float v = 0.f;
    if (g < 18) {
        int kh = g / 6, r6 = g % 6;
        int kw = r6 >> 1, cg = r6 & 1;
        int ci = slot * 16 + cg * 8 + j;
        v = W[((size_t)(cell * 48 + co) * 48 + ci) * 9 + kh * 3 + kw];
    }
    Abuf[idx] = (_Float16)v;
}

// Per-cell I/O descriptor. Streams: fp16 NHWC, 130x130 pitch, zero border.
struct CellIO {
    const _Float16* in0; const _Float16* in1; const _Float16* in2;
    const _Float16* Ac; const float* bc;
    _Float16* o0; _Float16* o1; _Float16* o2;
    float* fout;
};

// ---------------------------------------------------------------------------
// One grid-cell conv body: slot-major implicit GEMM, fp16 A x fp16 B, fp32
// accumulate (validated r11-13). Staging:
//  - XIN (cell (0,0) only): fp32 NCHW x -> fp16, swizzled LDS (r9 pattern).
//  - else: async DMA. LDS unit l must hold logical unit swz(l) (involution),
//    so lane l's GLOBAL address is computed from u = swz(l); LDS dest is the
//    wave-uniform block base (+ lane*16 by HW). Padded border -> no bounds
//    checks; border is zero via the per-call armor memset.
// Block: 256 thr = 4 waves; wave w: rows 4w..4w+3 of a 16x16 px tile.
// ---------------------------------------------------------------------------
template<int LIVE, int NIN, bool FIN, bool XIN>
__device__ __forceinline__ void cell_body(const CellIO& P, int b, _Float16* xh,
                                          const float* xsrc)
{
    const int tid = threadIdx.x;
    const int bx = blockIdx.x, by = blockIdx.y;
    const int x0 = bx * 16, y0 = by * 16;
    const int lane = tid & 63, wv = tid >> 6;
    const int n = lane & 15, quad = lane >> 4;
    const int py0 = wv * 4;

    if constexpr (XIN) {
        // 288 row-tasks (ci16, iy18): fp32 NCHW, bounds-checked, cvt+swz write
        for (int task = tid; task < 288; task += 256) {
            int ci = task / 18, iy = task - (task / 18) * 18;
            float v[18];
#pragma unroll
            for (int ix = 0; ix < 18; ++ix) v[ix] = 0.f;
            int gy = y0 + iy - 1;
            if ((unsigned)gy < (unsigned)HW) {
                const float* rp = xsrc + (((size_t)b * 16 + ci) * HW + gy) * HW + x0;
                f32x4 q0 = *(const f32x4*)(rp);
                f32x4 q1 = *(const f32x4*)(rp + 4);
                f32x4 q2 = *(const f32x4*)(rp + 8);
                f32x4 q3 = *(const f32x4*)(rp + 12);
#pragma unroll
                for (int j = 0; j < 4; ++j) {
                    v[1 + j] = q0[j]; v[5 + j] = q1[j];
                    v[9 + j] = q2[j]; v[13 + j] = q3[j];
                }
                if (x0 > 0)       v[0]  = rp[-1];
                if (x0 < HW - 16) v[17] = rp[16];
            }
            int cg = ci >> 3, cj = ci & 7;
#pragma unroll
            for (int ix = 0; ix < 18; ++ix)
                xh[swz((iy * 18 + ix) * 2 + cg) * 8 + cj] = (_Float16)v[ix];
        }
    } else {
        const _Float16* const ins[3] = {P.in0, P.in1, P.in2};
#pragma unroll
        for (int s = 0; s < NIN; ++s) {
            // tile halo origin in padded coords = (by*16, bx*16)
            const _Float16* src = ins[s] + (size_t)b * (PW * PW * 16)
                                 + ((size_t)(by * 16) * PW + bx * 16) * 16;
            _Float16* base = xh + s * 5184;
            for (int k = wv; k < 10; k += 4) {     // 10 full 64-unit blocks
                int l = k * 64 + lane;
                int u = swz(l);                    // involution
                int p = u >> 1, hi = u & 1;
                int iy = p / 18, ix = p - iy * 18;
                GLD_LDS(src + (iy * PW + ix) * 16 + hi * 8, base + k * 512);
            }
            if (wv == 2 && lane < 8) {             // tail units 640..647 (swz-id)
                int u = 640 + lane;
                int p = u >> 1, hi = u & 1;
                int iy = p / 18, ix = p - iy * 18;
                *(half8*)(base + u * 8) =
                    *(const half8*)(src + (iy * PW + ix) * 16 + hi * 8);
            }
        }
    }
    __syncthreads();

    // Per-chunk B-read base (validated). Dead groups (g>=18) -> g=0 (A zero).
    int base_c[5];
#pragma unroll
    for (int c = 0; c < 5; ++c) {
        int g = c * 4 + quad;
        if (g >= 18) g = 0;
        int kh = g / 6, r6 = g % 6;
        int kw = r6 >> 1, cg = r6 & 1;
        base_c[c] = ((py0 + kh) * 18 + n + kw) * 2 + cg;
    }

    // acc[cot][nt]: co = cot*16 + quad*4 + r, pixel (y0+py0+nt, x0+n)
    f32x4 acc[3][4];
#pragma unroll
    for (int cot = 0; cot < 3; ++cot) {
        if (!(LIVE & (1 << cot))) continue;
#pragma unroll
        for (int r = 0; r < 4; ++r) {
            float bv = P.bc[cot * 16 + quad * 4 + r];
#pragma unroll
            for (int nt = 0; nt < 4; ++nt) acc[cot][nt][r] = bv;
        }
    }

    // ---- K loop: NIN slots x 5 chunks, fully unrolled, no barriers ----
#pragma unroll
    for (int s = 0; s < NIN; ++s) {
        const _Float16* sxh = xh + s * 5184;
        const _Float16* As = P.Ac + (size_t)(s * 5) * 1536 + quad * 384 + n * 8;
#pragma unroll
        for (int c = 0; c < 5; ++c) {
            half8 Bh[4];
#pragma unroll
            for (int nt = 0; nt < 4; ++nt)
                Bh[nt] = *(const half8*)(sxh + swz(base_c[c] + nt * 36) * 8);
            const _Float16* Ab = As + (size_t)c * 1536;
#pragma unroll
            for (int cot = 0; cot < 3; ++cot) {
                if (!(LIVE & (1 << cot))) continue;
                half8 ah = *(const half8*)(Ab + cot * 128);
#pragma unroll
                for (int nt = 0; nt < 4; ++nt)
                    acc[cot][nt] = __builtin_amdgcn_mfma_f32_16x16x32_f16(ah, Bh[nt], acc[cot][nt], 0, 0, 0);
            }
        }
    }

    // ---- epilogue ----
    if constexpr (FIN) {
        // final cell: fp32 NCHW scatter to d_out (validated path)
#pragma unroll
        for (int nt = 0; nt < 4; ++nt) {
            int y = y0 + py0 + nt, xg = x0 + n;
#pragma unroll
            for (int r = 0; r < 4; ++r) {
                float vv = acc[0][nt][r];
                P.fout[(((size_t)b * 16 + quad * 4 + r) * HW + y) * HW + xg] = vv > 0.f ? vv : 0.f;
            }
        }
    } else {
        // fp16 NHWC stores into padded interior (+1,+1)
        _Float16* const outs[3] = {P.o0, P.o1, P.o2};
#pragma unroll
        for (int cot = 0; cot < 3; ++cot) {
            if (!(LIVE & (1 << cot))) continue;
            _Float16* op = outs[cot] + (size_t)b * (PW * PW * 16);
#pragma unroll
            for (int nt = 0; nt < 4; ++nt) {
                int y = y0 + py0 + nt;
                half4 hv;
#pragma unroll
                for (int r = 0; r < 4; ++r) {
                    float vv = acc[cot][nt][r];
                    hv[r] = (_Float16)(vv > 0.f ? vv : 0.f);
                }
                *(half4*)(op + ((size_t)(y + 1) * PW + x0 + n + 1) * 16 + quad * 4) = hv;
            }
        }
    }
}

// ---------------------------------------------------------------------------
// Stage kernel: one or two independent cells per launch. blockIdx.z < 8 ->
// cell 0 (batch z), z >= 8 -> cell 1 (batch z-8). L1==0 -> single-cell.
// LDS: MAXN * 10368 B (31.1 KB at NIN=3) -> 4 blocks/CU.
// ---------------------------------------------------------------------------
template<int L0, int N0, int L1, int N1, bool FIN, bool XIN>
__global__ __launch_bounds__(256, 4) void cell_k(CellIO P0, CellIO P1,
                                                 const float* xsrc) {
    constexpr int MAXN = (N0 > N1) ? N0 : N1;
    __shared__ __align__(16) _Float16 xh[MAXN * 5184];
    int b = blockIdx.z & 7;
    if constexpr (L1 > 0) {
        if (blockIdx.z >= 8) { cell_body<L1, N1, false, false>(P1, b, xh, nullptr); return; }
    }
    cell_body<L0, N0, FIN, XIN>(P0, b, xh, xsrc);
}

// ---------------------------------------------------------------------------
// Orchestration: anti-diagonal stage schedule s = 2*col + row (validated r5;
// r14's persistent dataflow regressed 9x — cross-XCD flag propagation is
// eviction-paced; reverted). Buffers: padded 130x130 fp16 NHWC (4.33 MB):
// R[colpar][row] x8, U[1..3] x3, D[2][2] x4 (r12/r13 scheme). Cell (0,0)
// reads fp32 x directly (x_prep folded in).
//
// DETERMINISM ARMOR (r12, keep — now also zeroes the padded borders, which
// staging DMA relies on): harness re-poisons d_ws 0xAA each call; zeroing the
// stream region every call makes each call bit-identical to the validated
// first call. ws: Abuf 0.74 + 15 x 4.33 = ~65.7 MB (harness provides >=127).
// ---------------------------------------------------------------------------
extern "C" void kernel_launch(void* const* d_in, const int* in_sizes, int n_in,
                              void* d_out, int out_size, void* d_ws, size_t ws_size,
                              hipStream_t stream) {
    const float* x  = (const float*)d_in[0];   // [8,16,128,128]
    const float* W  = (const float*)d_in[1];   // [4,4,48,48,3,3]
    const float* bi = (const float*)d_in[2];   // [4,4,48]
    float* out = (float*)d_out;                // [8,16,128,128]

    _Float16* Abuf = (_Float16*)d_ws;
    const size_t abytes = (size_t)NCELL * ABUF_PER_CELL * 2;   // 0.74 MB
    _Float16* q = (_Float16*)((char*)d_ws + abytes);
    const size_t S = (size_t)8 * PW * PW * 16;                 // halfs/buffer

    // Armor: zero all 15 stream buffers (incl. borders) every call.
    hipMemsetAsync((void*)q, 0, (size_t)15 * S * 2, stream);

    _Float16 *R[2][4], *U[4], *D[2][2];
    for (int pa = 0; pa < 2; ++pa)
        for (int r = 0; r < 4; ++r) { R[pa][r] = q; q += S; }
    U[0] = nullptr;
    for (int r = 1; r < 4; ++r) { U[r] = q; q += S; }
    D[0][0] = q; q += S; D[0][1] = q; q += S;
    D[1][0] = q; q += S; D[1][1] = q; q += S;

    hipLaunchKernelGGL(prep_w_k, dim3((NCELL * ABUF_PER_CELL + 255) / 256),
                       dim3(256), 0, stream, W, Abuf);

    auto mkio = [&](int c, int r) -> CellIO {
        CellIO io{};
        if (c == 0) {
            io.in0 = (r == 0) ? nullptr : D[0][(r - 1) & 1];   // r==0: XIN
        } else {
            io.in0 = R[(c - 1) & 1][r];
            if (r == 0)      io.in1 = U[1];
            else if (r == 3) io.in1 = D[c & 1][0];
            else { io.in1 = U[r + 1]; io.in2 = D[c & 1][(r - 1) & 1]; }
        }
        if (c < 3) {
            io.o0 = R[c & 1][r];
            if (r > 0) io.o1 = U[r];
            if (r < 3) io.o2 = D[c & 1][r & 1];
        } else {
            if (r < 3) io.o2 = D[1][r & 1];
            else       io.fout = out;
        }
        io.Ac = Abuf + (size_t)(c * 4 + r) * ABUF_PER_CELL;
        io.bc = bi + (size_t)(c * 4 + r) * 48;
        return io;
    };

    dim3 blk(256), g1(8, 8, 8), g2(8, 8, 16);
#define ONEX(c, r)       do { CellIO a = mkio(c, r); \
    hipLaunchKernelGGL((cell_k<5, 1, 0, 0, false, true>), g1, blk, 0, stream, a, a, x); } while (0)
#define ONE(L, N, c, r)  do { CellIO a = mkio(c, r); \
    hipLaunchKernelGGL((cell_k<L, N, 0, 0, false, false>), g1, blk, 0, stream, a, a, x); } while (0)
#define ONEF(c, r)       do { CellIO a = mkio(c, r); \
    hipLaunchKernelGGL((cell_k<1, 2, 0, 0, true, false>), g1, blk, 0, stream, a, a, x); } while (0)
#define TWO(L0, N0, c0, r0, L1, N1, c1, r1) do { \
    CellIO a = mkio(c0, r0), bb2 = mkio(c1, r1); \
    hipLaunchKernelGGL((cell_k<L0, N0, L1, N1, false, false>), g2, blk, 0, stream, a, bb2, x); } while (0)

    ONEX(0, 0);
    ONE(7, 1, 0, 1);
    TWO(7, 1, 0, 2,  5, 2, 1, 0);
    TWO(3, 1, 0, 3,  7, 3, 1, 1);
    TWO(7, 3, 1, 2,  5, 2, 2, 0);
    TWO(3, 2, 1, 3,  7, 3, 2, 1);
    TWO(7, 3, 2, 2,  4, 2, 3, 0);
    TWO(3, 2, 2, 3,  4, 3, 3, 1);
    ONE(4, 3, 3, 2);
    ONEF(3, 3);
#undef ONEX
#undef ONE
#undef ONEF
#undef TWO
}

// Round 16
// 199.525 us; speedup vs baseline: 9.4661x; 1.0415x over previous
//
#include <hip/hip_runtime.h>

// Problem constants
#define HW    128
#define PW    130          // padded stream pitch (1-px zero border)
#define NCELL 16
#define ABUF_PER_CELL 23040   // 3 slots * 5 chunks * 4 quads * 48 co * 8

typedef _Float16 half8 __attribute__((ext_vector_type(8)));
typedef _Float16 half4 __attribute__((ext_vector_type(4)));
typedef float    f32x4 __attribute__((ext_vector_type(4)));

// async global->LDS, 16 B per lane; LDS dest = wave-uniform base + lane*16
#define GLD_LDS(gp, lp) __builtin_amdgcn_global_load_lds( \
    (const __attribute__((address_space(1))) void*)(gp),  \
    (__attribute__((address_space(3))) void*)(lp), 16, 0, 0)

// ---------------------------------------------------------------------------
// Weight prep: W[cell][co][ci][kh][kw] fp32 -> slot-major A-fragment fp16
// (RTN). Abuf: [cell][slot3][chunk5][quad4][co48][j8]; k-group g = chunk*4 +
// quad -> (kh=g/6, kw=(g%6)/2, cg=g&1), ci = slot*16 + cg*8 + j; g>=18 -> 0.
// (Validated rounds 11-15: absmax 4.88e-4.)
// ---------------------------------------------------------------------------
__global__ void prep_w_k(const float* __restrict__ W, _Float16* __restrict__ Abuf) {
    int idx = blockIdx.x * 256 + threadIdx.x;
    if (idx >= NCELL * ABUF_PER_CELL) return;
    int j = idx & 7;
    int t = idx >> 3;
    int co = t % 48;   t /= 48;
    int quad = t & 3;  t >>= 2;
    int chunk = t % 5; t /= 5;
    int slot = t % 3;  t /= 3;
    int cell = t;
    int g = chunk * 4 + quad;
    float v = 0.f;
    if (g < 18) {
        int kh = g / 6, r6 = g % 6;
        int kw = r6 >> 1, cg = r6 & 1;
        int ci = slot * 16 + cg * 8 + j;
        v = W[((size_t)(cell * 48 + co) * 48 + ci) * 9 + kh * 3 + kw];
    }
    Abuf[idx] = (_Float16)v;
}

// Per-cell I/O descriptor. Streams: fp16 NHWC, 130x130 pitch, zero border.
struct CellIO {
    const _Float16* in0; const _Float16* in1; const _Float16* in2;
    const _Float16* Ac; const float* bc;
    _Float16* o0; _Float16* o1; _Float16* o2;
    float* fout;
};

// ---------------------------------------------------------------------------
// One grid-cell conv body: slot-major implicit GEMM, fp16 A x fp16 B, fp32
// accumulate (validated r11-15).
//
// LDS layout (r16, conflict-free): unit u = (iy*2 + cg)*18 + ix, 8 halfs per
// unit = channels [8cg, 8cg+8) of halo pixel (iy, ix). B-reads for a quad hit
// 16 CONSECUTIVE units (16 B apart) -> 2 bank-wraps -> conflict-free (the old
// (px*2+cg) layout had 32-B lane stride -> 4-way conflicts, 3.2M conflict
// cycles/dispatch; the XOR swizzle could not fix even-residue aliasing and is
// deleted). Unit contents are identical -> numerics bit-identical.
//
// Staging: XIN (cell (0,0)): fp32 NCHW x -> fp16 direct; else async DMA of
// 64-unit blocks (lane l -> unit k*64+l, decode u -> (iy,cg,ix) on the global
// address side). Padded border -> no bounds checks (zeroed by armor memset).
// Block: 256 thr = 4 waves; wave w: rows 4w..4w+3 of a 16x16 px tile.
// ---------------------------------------------------------------------------
template<int LIVE, int NIN, bool FIN, bool XIN>
__device__ __forceinline__ void cell_body(const CellIO& P, int b, _Float16* xh,
                                          const float* xsrc)
{
    const int tid = threadIdx.x;
    const int bx = blockIdx.x, by = blockIdx.y;
    const int x0 = bx * 16, y0 = by * 16;
    const int lane = tid & 63, wv = tid >> 6;
    const int n = lane & 15, quad = lane >> 4;
    const int py0 = wv * 4;

    if constexpr (XIN) {
        // 288 row-tasks (ci16, iy18): fp32 NCHW, bounds-checked, cvt write
        for (int task = tid; task < 288; task += 256) {
            int ci = task / 18, iy = task - (task / 18) * 18;
            float v[18];
#pragma unroll
            for (int ix = 0; ix < 18; ++ix) v[ix] = 0.f;
            int gy = y0 + iy - 1;
            if ((unsigned)gy < (unsigned)HW) {
                const float* rp = xsrc + (((size_t)b * 16 + ci) * HW + gy) * HW + x0;
                f32x4 q0 = *(const f32x4*)(rp);
                f32x4 q1 = *(const f32x4*)(rp + 4);
                f32x4 q2 = *(const f32x4*)(rp + 8);
                f32x4 q3 = *(const f32x4*)(rp + 12);
#pragma unroll
                for (int j = 0; j < 4; ++j) {
                    v[1 + j] = q0[j]; v[5 + j] = q1[j];
                    v[9 + j] = q2[j]; v[13 + j] = q3[j];
                }
                if (x0 > 0)       v[0]  = rp[-1];
                if (x0 < HW - 16) v[17] = rp[16];
            }
            int cg = ci >> 3, cj = ci & 7;
#pragma unroll
            for (int ix = 0; ix < 18; ++ix)
                xh[(((iy * 2 + cg) * 18) + ix) * 8 + cj] = (_Float16)v[ix];
        }
    } else {
        const _Float16* const ins[3] = {P.in0, P.in1, P.in2};
#pragma unroll
        for (int s = 0; s < NIN; ++s) {
            // tile halo origin in padded coords = (by*16, bx*16)
            const _Float16* src = ins[s] + (size_t)b * (PW * PW * 16)
                                 + ((size_t)(by * 16) * PW + bx * 16) * 16;
            _Float16* base = xh + s * 5184;
            for (int k = wv; k < 10; k += 4) {     // 10 full 64-unit blocks
                int u = k * 64 + lane;
                int iy = u / 36, r36 = u - iy * 36;
                int cg = r36 / 18, ix = r36 - cg * 18;
                GLD_LDS(src + (iy * PW + ix) * 16 + cg * 8, base + k * 512);
            }
            if (wv == 2 && lane < 8) {             // tail units 640..647
                int u = 640 + lane;                // iy=17, cg=1, ix=10+lane
                int ix = u - 630;                  // (17*2+1)*18 = 630
                *(half8*)(base + u * 8) =
                    *(const half8*)(src + (17 * PW + ix) * 16 + 8);
            }
        }
    }
    __syncthreads();

    // Per-chunk B-read base unit. Dead groups (g>=18) -> g=0 (A zero there).
    int base_c[5];
#pragma unroll
    for (int c = 0; c < 5; ++c) {
        int g = c * 4 + quad;
        if (g >= 18) g = 0;
        int kh = g / 6, r6 = g % 6;
        int kw = r6 >> 1, cg = r6 & 1;
        base_c[c] = ((py0 + kh) * 2 + cg) * 18 + n + kw;
    }

    // acc[cot][nt]: co = cot*16 + quad*4 + r, pixel (y0+py0+nt, x0+n)
    f32x4 acc[3][4];
#pragma unroll
    for (int cot = 0; cot < 3; ++cot) {
        if (!(LIVE & (1 << cot))) continue;
#pragma unroll
        for (int r = 0; r < 4; ++r) {
            float bv = P.bc[cot * 16 + quad * 4 + r];
#pragma unroll
            for (int nt = 0; nt < 4; ++nt) acc[cot][nt][r] = bv;
        }
    }

    // ---- K loop: NIN slots x 5 chunks, fully unrolled, no barriers ----
#pragma unroll
    for (int s = 0; s < NIN; ++s) {
        const _Float16* sxh = xh + s * 5184;
        const _Float16* As = P.Ac + (size_t)(s * 5) * 1536 + quad * 384 + n * 8;
#pragma unroll
        for (int c = 0; c < 5; ++c) {
            half8 Bh[4];
#pragma unroll
            for (int nt = 0; nt < 4; ++nt)
                Bh[nt] = *(const half8*)(sxh + (base_c[c] + nt * 36) * 8);
            const _Float16* Ab = As + (size_t)c * 1536;
#pragma unroll
            for (int cot = 0; cot < 3; ++cot) {
                if (!(LIVE & (1 << cot))) continue;
                half8 ah = *(const half8*)(Ab + cot * 128);
#pragma unroll
                for (int nt = 0; nt < 4; ++nt)
                    acc[cot][nt] = __builtin_amdgcn_mfma_f32_16x16x32_f16(ah, Bh[nt], acc[cot][nt], 0, 0, 0);
            }
        }
    }

    // ---- epilogue ----
    if constexpr (FIN) {
        // final cell: fp32 NCHW scatter to d_out (validated path)
#pragma unroll
        for (int nt = 0; nt < 4; ++nt) {
            int y = y0 + py0 + nt, xg = x0 + n;
#pragma unroll
            for (int r = 0; r < 4; ++r) {
                float vv = acc[0][nt][r];
                P.fout[(((size_t)b * 16 + quad * 4 + r) * HW + y) * HW + xg] = vv > 0.f ? vv : 0.f;
            }
        }
    } else {
        // fp16 NHWC stores into padded interior (+1,+1)
        _Float16* const outs[3] = {P.o0, P.o1, P.o2};
#pragma unroll
        for (int cot = 0; cot < 3; ++cot) {
            if (!(LIVE & (1 << cot))) continue;
            _Float16* op = outs[cot] + (size_t)b * (PW * PW * 16);
#pragma unroll
            for (int nt = 0; nt < 4; ++nt) {
                int y = y0 + py0 + nt;
                half4 hv;
#pragma unroll
                for (int r = 0; r < 4; ++r) {
                    float vv = acc[cot][nt][r];
                    hv[r] = (_Float16)(vv > 0.f ? vv : 0.f);
                }
                *(half4*)(op + ((size_t)(y + 1) * PW + x0 + n + 1) * 16 + quad * 4) = hv;
            }
        }
    }
}

// ---------------------------------------------------------------------------
// Stage kernel: one or two independent cells per launch. blockIdx.z < 8 ->
// cell 0 (batch z), z >= 8 -> cell 1 (batch z-8). L1==0 -> single-cell.
// LDS: MAXN * 10368 B (31.1 KB at NIN=3) -> 4 blocks/CU.
// ---------------------------------------------------------------------------
template<int L0, int N0, int L1, int N1, bool FIN, bool XIN>
__global__ __launch_bounds__(256, 4) void cell_k(CellIO P0, CellIO P1,
                                                 const float* xsrc) {
    constexpr int MAXN = (N0 > N1) ? N0 : N1;
    __shared__ __align__(16) _Float16 xh[MAXN * 5184];
    int b = blockIdx.z & 7;
    if constexpr (L1 > 0) {
        if (blockIdx.z >= 8) { cell_body<L1, N1, false, false>(P1, b, xh, nullptr); return; }
    }
    cell_body<L0, N0, FIN, XIN>(P0, b, xh, xsrc);
}

// ---------------------------------------------------------------------------
// Orchestration: anti-diagonal stage schedule s = 2*col + row (validated r5;
// depth-10 is the exact dependency-graph longest path — launch-minimal).
// Buffers: padded 130x130 fp16 NHWC (4.33 MB): R[colpar][row] x8, U[1..3] x3,
// D[2][2] x4. Cell (0,0) reads fp32 x directly.
//
// DETERMINISM ARMOR (r12, keep): harness re-poisons d_ws 0xAA each call; r11
// passed fresh-ws validation but diverged on replay (root cause never found
// statically — full R/U/D/WAR audit clean). Zeroing the stream region every
// call makes each call bit-identical to the validated first call, and zeroes
// the padded borders the staging DMA relies on. ws ~65.7 MB.
// ---------------------------------------------------------------------------
extern "C" void kernel_launch(void* const* d_in, const int* in_sizes, int n_in,
                              void* d_out, int out_size, void* d_ws, size_t ws_size,
                              hipStream_t stream) {
    const float* x  = (const float*)d_in[0];   // [8,16,128,128]
    const float* W  = (const float*)d_in[1];   // [4,4,48,48,3,3]
    const float* bi = (const float*)d_in[2];   // [4,4,48]
    float* out = (float*)d_out;                // [8,16,128,128]

    _Float16* Abuf = (_Float16*)d_ws;
    const size_t abytes = (size_t)NCELL * ABUF_PER_CELL * 2;   // 0.74 MB
    _Float16* q = (_Float16*)((char*)d_ws + abytes);
    const size_t S = (size_t)8 * PW * PW * 16;                 // halfs/buffer

    // Armor: zero all 15 stream buffers (incl. borders) every call.
    hipMemsetAsync((void*)q, 0, (size_t)15 * S * 2, stream);

    _Float16 *R[2][4], *U[4], *D[2][2];
    for (int pa = 0; pa < 2; ++pa)
        for (int r = 0; r < 4; ++r) { R[pa][r] = q; q += S; }
    U[0] = nullptr;
    for (int r = 1; r < 4; ++r) { U[r] = q; q += S; }
    D[0][0] = q; q += S; D[0][1] = q; q += S;
    D[1][0] = q; q += S; D[1][1] = q; q += S;

    hipLaunchKernelGGL(prep_w_k, dim3((NCELL * ABUF_PER_CELL + 255) / 256),
                       dim3(256), 0, stream, W, Abuf);

    auto mkio = [&](int c, int r) -> CellIO {
        CellIO io{};
        if (c == 0) {
            io.in0 = (r == 0) ? nullptr : D[0][(r - 1) & 1];   // r==0: XIN
        } else {
            io.in0 = R[(c - 1) & 1][r];
            if (r == 0)      io.in1 = U[1];
            else if (r == 3) io.in1 = D[c & 1][0];
            else { io.in1 = U[r + 1]; io.in2 = D[c & 1][(r - 1) & 1]; }
        }
        if (c < 3) {
            io.o0 = R[c & 1][r];
            if (r > 0) io.o1 = U[r];
            if (r < 3) io.o2 = D[c & 1][r & 1];
        } else {
            if (r < 3) io.o2 = D[1][r & 1];
            else       io.fout = out;
        }
        io.Ac = Abuf + (size_t)(c * 4 + r) * ABUF_PER_CELL;
        io.bc = bi + (size_t)(c * 4 + r) * 48;
        return io;
    };

    dim3 blk(256), g1(8, 8, 8), g2(8, 8, 16);
#define ONEX(c, r)       do { CellIO a = mkio(c, r); \
    hipLaunchKernelGGL((cell_k<5, 1, 0, 0, false, true>), g1, blk, 0, stream, a, a, x); } while (0)
#define ONE(L, N, c, r)  do { CellIO a = mkio(c, r); \
    hipLaunchKernelGGL((cell_k<L, N, 0, 0, false, false>), g1, blk, 0, stream, a, a, x); } while (0)
#define ONEF(c, r)       do { CellIO a = mkio(c, r); \
    hipLaunchKernelGGL((cell_k<1, 2, 0, 0, true, false>), g1, blk, 0, stream, a, a, x); } while (0)
#define TWO(L0, N0, c0, r0, L1, N1, c1, r1) do { \
    CellIO a = mkio(c0, r0), bb2 = mkio(c1, r1); \
    hipLaunchKernelGGL((cell_k<L0, N0, L1, N1, false, false>), g2, blk, 0, stream, a, bb2, x); } while (0)

    ONEX(0, 0);
    ONE(7, 1, 0, 1);
    TWO(7, 1, 0, 2,  5, 2, 1, 0);
    TWO(3, 1, 0, 3,  7, 3, 1, 1);
    TWO(7, 3, 1, 2,  5, 2, 2, 0);
    TWO(3, 2, 1, 3,  7, 3, 2, 1);
    TWO(7, 3, 2, 2,  4, 2, 3, 0);
    TWO(3, 2, 2, 3,  4, 3, 3, 1);
    ONE(4, 3, 3, 2);
    ONEF(3, 3);
#undef ONEX
#undef ONE
#undef ONEF
#undef TWO
}

// Round 18
// 198.933 us; speedup vs baseline: 9.4943x; 1.0030x over previous
//
#include <hip/hip_runtime.h>

// Problem constants
#define HW    128
#define PW    130          // padded stream pitch (1-px zero border)
#define NCELL 16
#define ABUF_PER_CELL 23040   // 3 slots * 5 chunks * 4 quads * 48 co * 8

typedef _Float16 half8 __attribute__((ext_vector_type(8)));
typedef _Float16 half4 __attribute__((ext_vector_type(4)));
typedef float    f32x4 __attribute__((ext_vector_type(4)));

// async global->LDS, 16 B per lane; LDS dest = wave-uniform base + lane*16
#define GLD_LDS(gp, lp) __builtin_amdgcn_global_load_lds( \
    (const __attribute__((address_space(1))) void*)(gp),  \
    (__attribute__((address_space(3))) void*)(lp), 16, 0, 0)

// ---------------------------------------------------------------------------
// Weight prep: W[cell][co][ci][kh][kw] fp32 -> slot-major A-fragment fp16
// (RTN). Abuf: [cell][slot3][chunk5][quad4][co48][j8]; k-group g = chunk*4 +
// quad -> (kh=g/6, kw=(g%6)/2, cg=g&1), ci = slot*16 + cg*8 + j; g>=18 -> 0.
// (Validated rounds 11-16: absmax 4.88e-4.)
// ---------------------------------------------------------------------------
__global__ void prep_w_k(const float* __restrict__ W, _Float16* __restrict__ Abuf) {
    int idx = blockIdx.x * 256 + threadIdx.x;
    if (idx >= NCELL * ABUF_PER_CELL) return;
    int j = idx & 7;
    int t = idx >> 3;
    int co = t % 48;   t /= 48;
    int quad = t & 3;  t >>= 2;
    int chunk = t % 5; t /= 5;
    int slot = t % 3;  t /= 3;
    int cell = t;
    int g = chunk * 4 + quad;
    float v = 0.f;
    if (g < 18) {
        int kh = g / 6, r6 = g % 6;
        int kw = r6 >> 1, cg = r6 & 1;
        int ci = slot * 16 + cg * 8 + j;
        v = W[((size_t)(cell * 48 + co) * 48 + ci) * 9 + kh * 3 + kw];
    }
    Abuf[idx] = (_Float16)v;
}

// Per-cell I/O descriptor. Streams: fp16 NHWC, 130x130 pitch, zero border.
struct CellIO {
    const _Float16* in0; const _Float16* in1; const _Float16* in2;
    const _Float16* Ac; const float* bc;
    _Float16* o0; _Float16* o1; _Float16* o2;
    float* fout;
};

// ---------------------------------------------------------------------------
// One grid-cell conv body: slot-major implicit GEMM, fp16 A x fp16 B, fp32
// accumulate (validated r11-16).
//
// LDS layout (r16, conflict-free): unit u = (iy*2 + cg)*18 + ix, 8 halfs per
// unit = channels [8cg, 8cg+8) of halo pixel (iy, ix). B-reads for a quad hit
// 16 CONSECUTIVE units (16 B apart) -> 2 bank-wraps -> conflict-free.
//
// Staging: XIN (cell (0,0)): fp32 NCHW x -> fp16 direct; else async DMA of
// 64-unit blocks (lane l -> unit k*64+l, decode u -> (iy,cg,ix) on the global
// address side). Padded border -> no bounds checks (zeroed by armor memset).
// Block: 256 thr = 4 waves; wave w: rows 4w..4w+3 of a 16x16 px tile.
// ---------------------------------------------------------------------------
template<int LIVE, int NIN, bool FIN, bool XIN>
__device__ __forceinline__ void cell_body(const CellIO& P, int b, _Float16* xh,
                                          const float* xsrc)
{
    const int tid = threadIdx.x;
    const int bx = blockIdx.x, by = blockIdx.y;
    const int x0 = bx * 16, y0 = by * 16;
    const int lane = tid & 63, wv = tid >> 6;
    const int n = lane & 15, quad = lane >> 4;
    const int py0 = wv * 4;

    if constexpr (XIN) {
        // 288 row-tasks (ci16, iy18): fp32 NCHW, bounds-checked, cvt write
        for (int task = tid; task < 288; task += 256) {
            int ci = task / 18, iy = task - (task / 18) * 18;
            float v[18];
#pragma unroll
            for (int ix = 0; ix < 18; ++ix) v[ix] = 0.f;
            int gy = y0 + iy - 1;
            if ((unsigned)gy < (unsigned)HW) {
                const float* rp = xsrc + (((size_t)b * 16 + ci) * HW + gy) * HW + x0;
                f32x4 q0 = *(const f32x4*)(rp);
                f32x4 q1 = *(const f32x4*)(rp + 4);
                f32x4 q2 = *(const f32x4*)(rp + 8);
                f32x4 q3 = *(const f32x4*)(rp + 12);
#pragma unroll
                for (int j = 0; j < 4; ++j) {
                    v[1 + j] = q0[j]; v[5 + j] = q1[j];
                    v[9 + j] = q2[j]; v[13 + j] = q3[j];
                }
                if (x0 > 0)       v[0]  = rp[-1];
                if (x0 < HW - 16) v[17] = rp[16];
            }
            int cg = ci >> 3, cj = ci & 7;
#pragma unroll
            for (int ix = 0; ix < 18; ++ix)
                xh[(((iy * 2 + cg) * 18) + ix) * 8 + cj] = (_Float16)v[ix];
        }
    } else {
        const _Float16* const ins[3] = {P.in0, P.in1, P.in2};
#pragma unroll
        for (int s = 0; s < NIN; ++s) {
            // tile halo origin in padded coords = (by*16, bx*16)
            const _Float16* src = ins[s] + (size_t)b * (PW * PW * 16)
                                 + ((size_t)(by * 16) * PW + bx * 16) * 16;
            _Float16* base = xh + s * 5184;
            for (int k = wv; k < 10; k += 4) {     // 10 full 64-unit blocks
                int u = k * 64 + lane;
                int iy = u / 36, r36 = u - iy * 36;
                int cg = r36 / 18, ix = r36 - cg * 18;
                GLD_LDS(src + (iy * PW + ix) * 16 + cg * 8, base + k * 512);
            }
            if (wv == 2 && lane < 8) {             // tail units 640..647
                int u = 640 + lane;                // iy=17, cg=1, ix=10+lane
                int ix = u - 630;                  // (17*2+1)*18 = 630
                *(half8*)(base + u * 8) =
                    *(const half8*)(src + (17 * PW + ix) * 16 + 8);
            }
        }
    }
    __syncthreads();

    // Per-chunk B-read base unit. Dead groups (g>=18) -> g=0 (A zero there).
    int base_c[5];
#pragma unroll
    for (int c = 0; c < 5; ++c) {
        int g = c * 4 + quad;
        if (g >= 18) g = 0;
        int kh = g / 6, r6 = g % 6;
        int kw = r6 >> 1, cg = r6 & 1;
        base_c[c] = ((py0 + kh) * 2 + cg) * 18 + n + kw;
    }

    // acc[cot][nt]: co = cot*16 + quad*4 + r, pixel (y0+py0+nt, x0+n)
    f32x4 acc[3][4];
#pragma unroll
    for (int cot = 0; cot < 3; ++cot) {
        if (!(LIVE & (1 << cot))) continue;
#pragma unroll
        for (int r = 0; r < 4; ++r) {
            float bv = P.bc[cot * 16 + quad * 4 + r];
#pragma unroll
            for (int nt = 0; nt < 4; ++nt) acc[cot][nt][r] = bv;
        }
    }

    // ---- K loop: NIN slots x 5 chunks, fully unrolled, no barriers ----
#pragma unroll
    for (int s = 0; s < NIN; ++s) {
        const _Float16* sxh = xh + s * 5184;
        const _Float16* As = P.Ac + (size_t)(s * 5) * 1536 + quad * 384 + n * 8;
#pragma unroll
        for (int c = 0; c < 5; ++c) {
            half8 Bh[4];
#pragma unroll
            for (int nt = 0; nt < 4; ++nt)
                Bh[nt] = *(const half8*)(sxh + (base_c[c] + nt * 36) * 8);
            const _Float16* Ab = As + (size_t)c * 1536;
#pragma unroll
            for (int cot = 0; cot < 3; ++cot) {
                if (!(LIVE & (1 << cot))) continue;
                half8 ah = *(const half8*)(Ab + cot * 128);
#pragma unroll
                for (int nt = 0; nt < 4; ++nt)
                    acc[cot][nt] = __builtin_amdgcn_mfma_f32_16x16x32_f16(ah, Bh[nt], acc[cot][nt], 0, 0, 0);
            }
        }
    }

    // ---- epilogue ----
    if constexpr (FIN) {
        // final cell: fp32 NCHW scatter to d_out (validated path)
#pragma unroll
        for (int nt = 0; nt < 4; ++nt) {
            int y = y0 + py0 + nt, xg = x0 + n;
#pragma unroll
            for (int r = 0; r < 4; ++r) {
                float vv = acc[0][nt][r];
                P.fout[(((size_t)b * 16 + quad * 4 + r) * HW + y) * HW + xg] = vv > 0.f ? vv : 0.f;
            }
        }
    } else {
        // fp16 NHWC stores into padded interior (+1,+1)
        _Float16* const outs[3] = {P.o0, P.o1, P.o2};
#pragma unroll
        for (int cot = 0; cot < 3; ++cot) {
            if (!(LIVE & (1 << cot))) continue;
            _Float16* op = outs[cot] + (size_t)b * (PW * PW * 16);
#pragma unroll
            for (int nt = 0; nt < 4; ++nt) {
                int y = y0 + py0 + nt;
                half4 hv;
#pragma unroll
                for (int r = 0; r < 4; ++r) {
                    float vv = acc[cot][nt][r];
                    hv[r] = (_Float16)(vv > 0.f ? vv : 0.f);
                }
                *(half4*)(op + ((size_t)(y + 1) * PW + x0 + n + 1) * 16 + quad * 4) = hv;
            }
        }
    }
}

// ---------------------------------------------------------------------------
// Stage kernel: one or two independent cells per launch. blockIdx.z < 8 ->
// cell 0 (batch z), z >= 8 -> cell 1 (batch z-8). L1==0 -> single-cell.
// LDS: MAXN * 10368 B (31.1 KB at NIN=3) -> 4 blocks/CU.
// ---------------------------------------------------------------------------
template<int L0, int N0, int L1, int N1, bool FIN, bool XIN>
__global__ __launch_bounds__(256, 4) void cell_k(CellIO P0, CellIO P1,
                                                 const float* xsrc) {
    constexpr int MAXN = (N0 > N1) ? N0 : N1;
    __shared__ __align__(16) _Float16 xh[MAXN * 5184];
    int b = blockIdx.z & 7;
    if constexpr (L1 > 0) {
        if (blockIdx.z >= 8) { cell_body<L1, N1, false, false>(P1, b, xh, nullptr); return; }
    }
    cell_body<L0, N0, FIN, XIN>(P0, b, xh, xsrc);
}

// ---------------------------------------------------------------------------
// Orchestration: anti-diagonal stage schedule s = 2*col + row (validated r5;
// depth-10 is the exact dependency-graph longest path — launch-minimal).
// Buffers: padded 130x130 fp16 NHWC (4.33 MB): R[colpar][row] x8, U[1..3] x3,
// D[2][2] x4. Cell (0,0) reads fp32 x directly.
//
// Structural plateau note (r14/r17): both launch-fusion escape routes fail on
// this platform — hand-rolled cross-XCD flag dataflow is eviction-paced (9x
// regression, r14) and hipLaunchCooperativeKernel errors out at this
// grid/LDS/VGPR point and cannot survive graph capture (r17, stub output).
// The 10-stage serialized schedule is the legal minimum.
//
// DETERMINISM ARMOR (r12, keep): harness re-poisons d_ws 0xAA each call; r11
// passed fresh-ws validation but diverged on replay (root cause never found
// statically — full R/U/D/WAR audit clean). Zeroing the stream region every
// call makes each call bit-identical to the validated first call, and zeroes
// the padded borders the staging DMA relies on. ws ~65.7 MB.
// ---------------------------------------------------------------------------
extern "C" void kernel_launch(void* const* d_in, const int* in_sizes, int n_in,
                              void* d_out, int out_size, void* d_ws, size_t ws_size,
                              hipStream_t stream) {
    const float* x  = (const float*)d_in[0];   // [8,16,128,128]
    const float* W  = (const float*)d_in[1];   // [4,4,48,48,3,3]
    const float* bi = (const float*)d_in[2];   // [4,4,48]
    float* out = (float*)d_out;                // [8,16,128,128]

    _Float16* Abuf = (_Float16*)d_ws;
    const size_t abytes = (size_t)NCELL * ABUF_PER_CELL * 2;   // 0.74 MB
    _Float16* q = (_Float16*)((char*)d_ws + abytes);
    const size_t S = (size_t)8 * PW * PW * 16;                 // halfs/buffer

    // Armor: zero all 15 stream buffers (incl. borders) every call.
    hipMemsetAsync((void*)q, 0, (size_t)15 * S * 2, stream);

    _Float16 *R[2][4], *U[4], *D[2][2];
    for (int pa = 0; pa < 2; ++pa)
        for (int r = 0; r < 4; ++r) { R[pa][r] = q; q += S; }
    U[0] = nullptr;
    for (int r = 1; r < 4; ++r) { U[r] = q; q += S; }
    D[0][0] = q; q += S; D[0][1] = q; q += S;
    D[1][0] = q; q += S; D[1][1] = q; q += S;

    hipLaunchKernelGGL(prep_w_k, dim3((NCELL * ABUF_PER_CELL + 255) / 256),
                       dim3(256), 0, stream, W, Abuf);

    auto mkio = [&](int c, int r) -> CellIO {
        CellIO io{};
        if (c == 0) {
            io.in0 = (r == 0) ? nullptr : D[0][(r - 1) & 1];   // r==0: XIN
        } else {
            io.in0 = R[(c - 1) & 1][r];
            if (r == 0)      io.in1 = U[1];
            else if (r == 3) io.in1 = D[c & 1][0];
            else { io.in1 = U[r + 1]; io.in2 = D[c & 1][(r - 1) & 1]; }
        }
        if (c < 3) {
            io.o0 = R[c & 1][r];
            if (r > 0) io.o1 = U[r];
            if (r < 3) io.o2 = D[c & 1][r & 1];
        } else {
            if (r < 3) io.o2 = D[1][r & 1];
            else       io.fout = out;
        }
        io.Ac = Abuf + (size_t)(c * 4 + r) * ABUF_PER_CELL;
        io.bc = bi + (size_t)(c * 4 + r) * 48;
        return io;
    };

    dim3 blk(256), g1(8, 8, 8), g2(8, 8, 16);
#define ONEX(c, r)       do { CellIO a = mkio(c, r); \
    hipLaunchKernelGGL((cell_k<5, 1, 0, 0, false, true>), g1, blk, 0, stream, a, a, x); } while (0)
#define ONE(L, N, c, r)  do { CellIO a = mkio(c, r); \
    hipLaunchKernelGGL((cell_k<L, N, 0, 0, false, false>), g1, blk, 0, stream, a, a, x); } while (0)
#define ONEF(c, r)       do { CellIO a = mkio(c, r); \
    hipLaunchKernelGGL((cell_k<1, 2, 0, 0, true, false>), g1, blk, 0, stream, a, a, x); } while (0)
#define TWO(L0, N0, c0, r0, L1, N1, c1, r1) do { \
    CellIO a = mkio(c0, r0), bb2 = mkio(c1, r1); \
    hipLaunchKernelGGL((cell_k<L0, N0, L1, N1, false, false>), g2, blk, 0, stream, a, bb2, x); } while (0)

    ONEX(0, 0);
    ONE(7, 1, 0, 1);
    TWO(7, 1, 0, 2,  5, 2, 1, 0);
    TWO(3, 1, 0, 3,  7, 3, 1, 1);
    TWO(7, 3, 1, 2,  5, 2, 2, 0);
    TWO(3, 2, 1, 3,  7, 3, 2, 1);
    TWO(7, 3, 2, 2,  4, 2, 3, 0);
    TWO(3, 2, 2, 3,  4, 3, 3, 1);
    ONE(4, 3, 3, 2);
    ONEF(3, 3);
#undef ONEX
#undef ONE
#undef ONEF
#undef TWO
}